// Round 1
// baseline (279.958 us; speedup 1.0000x reference)
//
#include <hip/hip_runtime.h>
#include <hip/hip_bf16.h>
#include <float.h>

#define N_ORB 1024
#define KSEL 32
#define LEAK 0.01f
#define LOG2E 1.4426950408889634f

typedef float f32x2 __attribute__((ext_vector_type(2)));
// NOTE: never write (f32x2)(a, b) — in C++ that's a comma-expr cast that
// SPLATS b. Use f32x2{a, b}.

__device__ __forceinline__ float leaky(float x) { return x >= 0.0f ? x : LEAK * x; }

// ---- DPP helpers ----
template <int CTRL, int RM>
__device__ __forceinline__ int dpp0_i(int v) {  // masked-off rows contribute 0
  return __builtin_amdgcn_update_dpp(0, v, CTRL, RM, 0xF, true);
}
template <int CTRL>
__device__ __forceinline__ float dpp_zero(float v) {
  return __int_as_float(
      __builtin_amdgcn_update_dpp(0, __float_as_int(v), CTRL, 0xF, 0xF, true));
}
__device__ __forceinline__ float rdlane(float v, int l) {
  return __int_as_float(__builtin_amdgcn_readlane(__float_as_int(v), l));
}

// full 64-lane float sum, uniform result
__device__ __forceinline__ float wave_sum64_dpp(float v) {
  v += dpp_zero<0x111>(v);
  v += dpp_zero<0x112>(v);
  v += dpp_zero<0x114>(v);
  v += dpp_zero<0x118>(v);
  v += dpp_zero<0x142>(v);
  v += dpp_zero<0x143>(v);
  return rdlane(v, 63);
}
// full 64-lane int sum, uniform result
__device__ __forceinline__ int wave_isum64(int v) {
  v += dpp0_i<0x111, 0xF>(v);
  v += dpp0_i<0x112, 0xF>(v);
  v += dpp0_i<0x114, 0xF>(v);
  v += dpp0_i<0x118, 0xF>(v);
  v += dpp0_i<0x142, 0xF>(v);
  v += dpp0_i<0x143, 0xF>(v);
  return __builtin_amdgcn_readlane(v, 63);
}
// 64-lane inclusive prefix sum (int), per-lane result
__device__ __forceinline__ int wave_iscan64(int v) {
  v += dpp0_i<0x111, 0xF>(v);
  v += dpp0_i<0x112, 0xF>(v);
  v += dpp0_i<0x114, 0xF>(v);
  v += dpp0_i<0x118, 0xF>(v);
  v += dpp0_i<0x142, 0xA>(v);
  v += dpp0_i<0x143, 0xC>(v);
  return v;
}

// Successive-softmax chain for TWO rows packed in f32x2 (.x=row0,.y=row1),
// multiplicative form (w tracks exp(s)). Element j of a row = lane*16 + j.
// om clamp folds to the VOP3 clamp modifier; equivalent to ref's 1e-20 floor
// at fp32 (khot deltas <= 1e-20, far below any top-32 boundary).
__device__ void run_chain2(f32x2 w[16], f32x2 kh[16]) {
#pragma unroll
  for (int i = 0; i < 16; ++i) kh[i] = f32x2{0.0f, 0.0f};
  const f32x2 onev = f32x2{1.0f, 1.0f};
  const f32x2 zerov = f32x2{0.0f, 0.0f};
  for (int it = 0; it < KSEL; ++it) {
    f32x2 t0 = w[0] + w[1], t1 = w[2] + w[3], t2 = w[4] + w[5], t3 = w[6] + w[7];
    f32x2 t4 = w[8] + w[9], t5 = w[10] + w[11], t6 = w[12] + w[13], t7 = w[14] + w[15];
    t0 += t1; t2 += t3; t4 += t5; t6 += t7;
    t0 += t2; t4 += t6;
    t0 += t4;
    float Z0 = wave_sum64_dpp(t0.x);  // independent of Z1 -> interleaved issue
    float Z1 = wave_sum64_dpp(t0.y);
    Z0 = fmaxf(Z0, 1e-30f);
    Z1 = fmaxf(Z1, 1e-30f);
    float r0 = __builtin_amdgcn_rcpf(Z0);
    float r1 = __builtin_amdgcn_rcpf(Z1);
    float rZ0 = __builtin_fmaf(__builtin_fmaf(-Z0, r0, 1.0f), r0, r0);
    float rZ1 = __builtin_fmaf(__builtin_fmaf(-Z1, r1, 1.0f), r1, r1);
    const f32x2 rZ = f32x2{rZ0, rZ1};
#pragma unroll
    for (int i = 0; i < 16; ++i) {
      kh[i] = __builtin_elementwise_fma(w[i], rZ, kh[i]);
      f32x2 om = __builtin_elementwise_fma(-w[i], rZ, onev);
      om = __builtin_elementwise_min(__builtin_elementwise_max(om, zerov), onev);
      w[i] = w[i] * om;
    }
  }
}

// Tie path for one row (cold). jax stable tie semantics: all >T, then ==T
// in ascending global index ((lane<<4)|slot).
__device__ unsigned tie_mask16(const f32x2 kh[16], bool comp_y, unsigned T,
                               int lane) {
  unsigned gt = 0, eq = 0;
#pragma unroll
  for (int i = 0; i < 16; ++i) {
    const unsigned u = __float_as_uint(comp_y ? kh[i].y : kh[i].x);
    gt |= (u > T ? 1u : 0u) << i;
    eq |= (u == T ? 1u : 0u) << i;
  }
  const int n_gt = wave_isum64(__popc(gt));
  const int m = 32 - n_gt;  // uniform, >= 1 by search invariant
  const int pe = __popc(eq);
  const int be = wave_iscan64(pe) - pe;
  int need = m - be;
  need = need < 0 ? 0 : (need > pe ? pe : need);
  unsigned tk = 0;
  unsigned em = eq;
  for (int guard = 0; guard < 16; ++guard) {
    if (!__any(need > 0)) break;
    if (need > 0) {
      const int bpos = __ffs(em) - 1;
      tk |= 1u << bpos;
      em &= em - 1;
      --need;
    }
  }
  return gt | tk;
}

// Top-32 for both packed rows: joint binary search on the uint views
// (khot >= 0 -> order-isomorphic), ballot+popcll counting, early exit when
// both rows exact. Invariant (r6/r7, field-validated): tie path always
// completes exactly 32.
__device__ void top32_mask2(const f32x2 kh[16], int lane, unsigned& m0,
                            unsigned& m1) {
  unsigned lo0 = 0, lo1 = 0;
  bool ex0 = false, ex1 = false;
  for (int b = 30; b >= 0; --b) {
    const unsigned c0v = lo0 | (1u << b);
    const unsigned c1v = lo1 | (1u << b);
    int c0 = 0, c1 = 0;
#pragma unroll
    for (int i = 0; i < 16; ++i) {
      c0 += __popcll(__ballot(__float_as_uint(kh[i].x) >= c0v));
      c1 += __popcll(__ballot(__float_as_uint(kh[i].y) >= c1v));
    }
    if (!ex0 && c0 >= 32) { lo0 = c0v; ex0 = (c0 == 32); }
    if (!ex1 && c1 >= 32) { lo1 = c1v; ex1 = (c1 == 32); }
    if (ex0 && ex1) break;
  }

  if (ex0) {
    unsigned mk = 0;
#pragma unroll
    for (int i = 0; i < 16; ++i)
      mk |= (__float_as_uint(kh[i].x) >= lo0 ? 1u : 0u) << i;
    m0 = mk;
  } else {
    m0 = tie_mask16(kh, false, lo0, lane);
  }
  if (ex1) {
    unsigned mk = 0;
#pragma unroll
    for (int i = 0; i < 16; ++i)
      mk |= (__float_as_uint(kh[i].y) >= lo1 ? 1u : 0u) << i;
    m1 = mk;
  } else {
    m1 = tie_mask16(kh, true, lo1, lane);
  }
}

// Compact the 32 selected global indices into dst[0..31], ascending order.
__device__ __forceinline__ void compact_idx(unsigned mask, int lane,
                                            int* __restrict__ dst) {
  const int pe = __popc(mask);
  int base = wave_iscan64(pe) - pe;
  unsigned m = mask;
  while (m) {
    const int s = __ffs(m) - 1;
    m &= m - 1;
    dst[base++] = (lane << 4) | s;
  }
}

__device__ __forceinline__ void write_half(float* __restrict__ dst,
                                           unsigned mask, int lane) {
  float4* o4 = (float4*)dst;
#pragma unroll
  for (int q = 0; q < 4; ++q) {
    float4 o;
    o.x = ((mask >> (4 * q + 0)) & 1) ? 1.0f : 0.0f;
    o.y = ((mask >> (4 * q + 1)) & 1) ? 1.0f : 0.0f;
    o.z = ((mask >> (4 * q + 2)) & 1) ? 1.0f : 0.0f;
    o.w = ((mask >> (4 * q + 3)) & 1) ? 1.0f : 0.0f;
    o4[lane * 4 + q] = o;
  }
}

// ---- precompute, stage 1 (grid 256): the two length-1024 dot layers ----
extern "C" __global__ void pcfs_pre1(const float* __restrict__ ba,
                                     const float* __restrict__ W1a,
                                     const float* __restrict__ b1a,
                                     const float* __restrict__ bb,
                                     const float* __restrict__ W1b,
                                     float* __restrict__ ws) {
  const int b = blockIdx.x;
  const int t = threadIdx.x;
  float acc = 0.0f;
  if (b < 128) {
#pragma unroll
    for (int j = t; j < N_ORB; j += 256) acc += ba[j] * W1a[j * 128 + b];
  } else {
    const int n = b - 128;
#pragma unroll
    for (int j = t; j < N_ORB; j += 256) acc += bb[j] * W1b[j * 128 + n];
  }
  __shared__ float red[4];
  float wsum = wave_sum64_dpp(acc);
  if ((t & 63) == 0) red[t >> 6] = wsum;
  __syncthreads();
  if (t == 0) {
    float tot = red[0] + red[1] + red[2] + red[3];
    if (b < 128)
      ws[1152 + b] = leaky(tot + b1a[b]);
    else
      ws[N_ORB + (b - 128)] = tot;
  }
}

// ---- precompute, stage 2 (1 block x 1024): h2 + alpha const logits ----
extern "C" __global__ void pcfs_pre2(const float* __restrict__ ba,
                                     const float* __restrict__ W2a,
                                     const float* __restrict__ b2a,
                                     const float* __restrict__ W3a,
                                     const float* __restrict__ b3a,
                                     float* __restrict__ ws) {
  __shared__ float h1[128];
  __shared__ float h2[64];
  const int t = threadIdx.x;
  if (t < 128) h1[t] = ws[1152 + t];
  __syncthreads();
  if (t < 64) {
    float acc = b2a[t];
#pragma unroll 8
    for (int n = 0; n < 128; ++n) acc += h1[n] * W2a[n * 64 + t];
    h2[t] = leaky(acc);
  }
  __syncthreads();
  float acc = b3a[t];
#pragma unroll 8
  for (int m = 0; m < 64; ++m) acc += h2[m] * W3a[m * N_ORB + t];
  ws[t] = acc + ba[t];  // + base_a
}

// One wave per PAIR of batch rows (.x=row0, .y=row1 in every f32x2).
extern "C" __global__ void __launch_bounds__(256, 4) pcfs_sampler(
    const float* __restrict__ ws, const float* __restrict__ Wc,
    const float* __restrict__ bc, const float* __restrict__ W1b,
    const float* __restrict__ b1b, const float* __restrict__ W2b,
    const float* __restrict__ b2b, const float* __restrict__ W3b,
    const float* __restrict__ b3b, const float* __restrict__ bb,
    const float* __restrict__ g_alpha, const float* __restrict__ g_beta,
    float* __restrict__ out, int B) {
  __shared__ int sidx[4][64];  // per-wave: [0..31]=row0 idxs, [32..63]=row1
  const int wave = threadIdx.x >> 6;
  const int lane = threadIdx.x & 63;
  const int pair = blockIdx.x * 4 + wave;
  const int row0 = pair * 2;
  if (row0 >= B) return;
  const bool have1 = (row0 + 1 < B);
  const int row1 = have1 ? row0 + 1 : row0;

  // ---- prefetch g_beta into registers NOW: these HBM loads drain ~10k
  // cycles later (beta exp2 stage), fully hidden behind the alpha phase ----
  float4 gb0[4], gb1[4];
  {
    const float4* g40 = (const float4*)(g_beta + (size_t)row0 * N_ORB);
    const float4* g41 = (const float4*)(g_beta + (size_t)row1 * N_ORB);
#pragma unroll
    for (int q = 0; q < 4; ++q) {
      gb0[q] = g40[lane * 4 + q];
      gb1[q] = g41[lane * 4 + q];
    }
  }

  f32x2 w[16], kh[16];

  // ---- alpha chains: w = exp2((const_logits + gumbel) * log2e), 2 rows ----
  {
    const float4* c4 = (const float4*)ws;
    const float4* g40 = (const float4*)(g_alpha + (size_t)row0 * N_ORB);
    const float4* g41 = (const float4*)(g_alpha + (size_t)row1 * N_ORB);
#pragma unroll
    for (int q = 0; q < 4; ++q) {
      float4 c = c4[lane * 4 + q];
      float4 g0 = g40[lane * 4 + q];
      float4 g1 = g41[lane * 4 + q];
      w[4 * q + 0] = f32x2{__builtin_amdgcn_exp2f((c.x + g0.x) * LOG2E),
                           __builtin_amdgcn_exp2f((c.x + g1.x) * LOG2E)};
      w[4 * q + 1] = f32x2{__builtin_amdgcn_exp2f((c.y + g0.y) * LOG2E),
                           __builtin_amdgcn_exp2f((c.y + g1.y) * LOG2E)};
      w[4 * q + 2] = f32x2{__builtin_amdgcn_exp2f((c.z + g0.z) * LOG2E),
                           __builtin_amdgcn_exp2f((c.z + g1.z) * LOG2E)};
      w[4 * q + 3] = f32x2{__builtin_amdgcn_exp2f((c.w + g0.w) * LOG2E),
                           __builtin_amdgcn_exp2f((c.w + g1.w) * LOG2E)};
    }
  }
  run_chain2(w, kh);
  unsigned am0, am1;
  top32_mask2(kh, lane, am0, am1);

  // write alpha halves (hard config: exact 0/1)
  write_half(out + (size_t)row0 * (2 * N_ORB), am0, lane);
  if (have1) write_half(out + (size_t)row1 * (2 * N_ORB), am1, lane);

  // ---- ctx = alpha_config @ Wc + bc, per row (LDS compact + fixed trip) ----
  compact_idx(am0, lane, &sidx[wave][0]);
  compact_idx(am1, lane, &sidx[wave][32]);
  const int vi0 = sidx[wave][lane & 31];
  const int vi1 = sidx[wave][32 + (lane & 31)];
  const float bcv = bc[lane & 31];
  float ctx0 = bcv, ctx1 = bcv;
#pragma unroll
  for (int r = 0; r < 32; ++r) {
    const int i0 = __builtin_amdgcn_readlane(vi0, r);  // uniform
    const int i1 = __builtin_amdgcn_readlane(vi1, r);
    ctx0 += Wc[i0 * 32 + (lane & 31)];
    ctx1 += Wc[i1 * 32 + (lane & 31)];
  }

  // ---- h1 = leaky(base_b@W1b[0:1024] + ctx@W1b[1024:1056] + b1b) ----
  f32x2 h1a, h1b_;
  {
    const float ia = b1b[lane] + ws[N_ORB + lane];
    const float ib = b1b[lane + 64] + ws[N_ORB + lane + 64];
    h1a = f32x2{ia, ia};
    h1b_ = f32x2{ib, ib};
  }
#pragma unroll 4
  for (int c = 0; c < 32; ++c) {
    const f32x2 cv = f32x2{rdlane(ctx0, c), rdlane(ctx1, c)};
    const float* wr = W1b + (size_t)(N_ORB + c) * 128;
    const float wa = wr[lane], wb = wr[lane + 64];
    h1a = __builtin_elementwise_fma(f32x2{wa, wa}, cv, h1a);
    h1b_ = __builtin_elementwise_fma(f32x2{wb, wb}, cv, h1b_);
  }
  h1a = f32x2{leaky(h1a.x), leaky(h1a.y)};
  h1b_ = f32x2{leaky(h1b_.x), leaky(h1b_.y)};

  // ---- h2 = leaky(h1 @ W2b + b2b): 4 partial accumulators (32-deep
  // chains instead of 128-deep) ----
  f32x2 h2p0, h2p1, h2p2, h2p3;
  {
    const float i2 = b2b[lane];
    h2p0 = f32x2{i2, i2};
    h2p1 = f32x2{0.0f, 0.0f};
    h2p2 = f32x2{0.0f, 0.0f};
    h2p3 = f32x2{0.0f, 0.0f};
  }
#pragma unroll 4
  for (int n = 0; n < 64; n += 4) {
    const f32x2 v0 = f32x2{rdlane(h1a.x, n + 0), rdlane(h1a.y, n + 0)};
    const f32x2 v1 = f32x2{rdlane(h1a.x, n + 1), rdlane(h1a.y, n + 1)};
    const f32x2 v2 = f32x2{rdlane(h1a.x, n + 2), rdlane(h1a.y, n + 2)};
    const f32x2 v3 = f32x2{rdlane(h1a.x, n + 3), rdlane(h1a.y, n + 3)};
    const float w0 = W2b[(n + 0) * 64 + lane];
    const float w1 = W2b[(n + 1) * 64 + lane];
    const float w2 = W2b[(n + 2) * 64 + lane];
    const float w3 = W2b[(n + 3) * 64 + lane];
    h2p0 = __builtin_elementwise_fma(f32x2{w0, w0}, v0, h2p0);
    h2p1 = __builtin_elementwise_fma(f32x2{w1, w1}, v1, h2p1);
    h2p2 = __builtin_elementwise_fma(f32x2{w2, w2}, v2, h2p2);
    h2p3 = __builtin_elementwise_fma(f32x2{w3, w3}, v3, h2p3);
  }
#pragma unroll 4
  for (int n = 0; n < 64; n += 4) {
    const f32x2 v0 = f32x2{rdlane(h1b_.x, n + 0), rdlane(h1b_.y, n + 0)};
    const f32x2 v1 = f32x2{rdlane(h1b_.x, n + 1), rdlane(h1b_.y, n + 1)};
    const f32x2 v2 = f32x2{rdlane(h1b_.x, n + 2), rdlane(h1b_.y, n + 2)};
    const f32x2 v3 = f32x2{rdlane(h1b_.x, n + 3), rdlane(h1b_.y, n + 3)};
    const float w0 = W2b[(n + 64 + 0) * 64 + lane];
    const float w1 = W2b[(n + 64 + 1) * 64 + lane];
    const float w2 = W2b[(n + 64 + 2) * 64 + lane];
    const float w3 = W2b[(n + 64 + 3) * 64 + lane];
    h2p0 = __builtin_elementwise_fma(f32x2{w0, w0}, v0, h2p0);
    h2p1 = __builtin_elementwise_fma(f32x2{w1, w1}, v1, h2p1);
    h2p2 = __builtin_elementwise_fma(f32x2{w2, w2}, v2, h2p2);
    h2p3 = __builtin_elementwise_fma(f32x2{w3, w3}, v3, h2p3);
  }
  f32x2 h2v = (h2p0 + h2p1) + (h2p2 + h2p3);
  h2v = f32x2{leaky(h2v.x), leaky(h2v.y)};

  // ---- beta logits: acc (in w[]) = h2 @ W3b + b3b; shared W3b loads,
  // unrolled x4 so 16 float4 loads pipeline per group ----
  {
    const float4* b4 = (const float4*)b3b;
#pragma unroll
    for (int q = 0; q < 4; ++q) {
      float4 b = b4[lane * 4 + q];
      w[4 * q + 0] = f32x2{b.x, b.x};
      w[4 * q + 1] = f32x2{b.y, b.y};
      w[4 * q + 2] = f32x2{b.z, b.z};
      w[4 * q + 3] = f32x2{b.w, b.w};
    }
  }
#pragma unroll 4
  for (int m = 0; m < 64; ++m) {
    const f32x2 hm = f32x2{rdlane(h2v.x, m), rdlane(h2v.y, m)};
    const float4* w4 = (const float4*)(W3b + m * N_ORB);
#pragma unroll
    for (int q = 0; q < 4; ++q) {
      float4 wv = w4[lane * 4 + q];
      w[4 * q + 0] = __builtin_elementwise_fma(f32x2{wv.x, wv.x}, hm, w[4 * q + 0]);
      w[4 * q + 1] = __builtin_elementwise_fma(f32x2{wv.y, wv.y}, hm, w[4 * q + 1]);
      w[4 * q + 2] = __builtin_elementwise_fma(f32x2{wv.z, wv.z}, hm, w[4 * q + 2]);
      w[4 * q + 3] = __builtin_elementwise_fma(f32x2{wv.w, wv.w}, hm, w[4 * q + 3]);
    }
  }
  // + base_b + gumbel (prefetched) -> w = exp2(logits * log2e)
  {
    const float4* bb4 = (const float4*)bb;
#pragma unroll
    for (int q = 0; q < 4; ++q) {
      float4 b = bb4[lane * 4 + q];
      const float4 g0 = gb0[q];
      const float4 g1 = gb1[q];
      w[4 * q + 0] = f32x2{
          __builtin_amdgcn_exp2f((w[4 * q + 0].x + b.x + g0.x) * LOG2E),
          __builtin_amdgcn_exp2f((w[4 * q + 0].y + b.x + g1.x) * LOG2E)};
      w[4 * q + 1] = f32x2{
          __builtin_amdgcn_exp2f((w[4 * q + 1].x + b.y + g0.y) * LOG2E),
          __builtin_amdgcn_exp2f((w[4 * q + 1].y + b.y + g1.y) * LOG2E)};
      w[4 * q + 2] = f32x2{
          __builtin_amdgcn_exp2f((w[4 * q + 2].x + b.z + g0.z) * LOG2E),
          __builtin_amdgcn_exp2f((w[4 * q + 2].y + b.z + g1.z) * LOG2E)};
      w[4 * q + 3] = f32x2{
          __builtin_amdgcn_exp2f((w[4 * q + 3].x + b.w + g0.w) * LOG2E),
          __builtin_amdgcn_exp2f((w[4 * q + 3].y + b.w + g1.w) * LOG2E)};
    }
  }
  run_chain2(w, kh);
  unsigned bm0, bm1;
  top32_mask2(kh, lane, bm0, bm1);

  write_half(out + (size_t)row0 * (2 * N_ORB) + N_ORB, bm0, lane);
  if (have1) write_half(out + (size_t)row1 * (2 * N_ORB) + N_ORB, bm1, lane);
}

extern "C" void kernel_launch(void* const* d_in, const int* in_sizes, int n_in,
                              void* d_out, int out_size, void* d_ws, size_t ws_size,
                              hipStream_t stream) {
  const float* ba  = (const float*)d_in[0];
  const float* W1a = (const float*)d_in[1];
  const float* b1a = (const float*)d_in[2];
  const float* W2a = (const float*)d_in[3];
  const float* b2a = (const float*)d_in[4];
  const float* W3a = (const float*)d_in[5];
  const float* b3a = (const float*)d_in[6];
  const float* bb  = (const float*)d_in[7];
  const float* Wc  = (const float*)d_in[8];
  const float* bc  = (const float*)d_in[9];
  const float* W1b = (const float*)d_in[10];
  const float* b1b = (const float*)d_in[11];
  const float* W2b = (const float*)d_in[12];
  const float* b2b = (const float*)d_in[13];
  const float* W3b = (const float*)d_in[14];
  const float* b3b = (const float*)d_in[15];
  const float* ga  = (const float*)d_in[16];
  const float* gbt = (const float*)d_in[17];
  const int B = in_sizes[16] / N_ORB;
  float* ws = (float*)d_ws;

  hipLaunchKernelGGL(pcfs_pre1, dim3(256), dim3(256), 0, stream,
                     ba, W1a, b1a, bb, W1b, ws);
  hipLaunchKernelGGL(pcfs_pre2, dim3(1), dim3(1024), 0, stream,
                     ba, W2a, b2a, W3a, b3a, ws);
  const int pairs = (B + 1) / 2;
  hipLaunchKernelGGL(pcfs_sampler, dim3((pairs + 3) / 4), dim3(256), 0, stream,
                     ws, Wc, bc, W1b, b1b, W2b, b2b, W3b, b3b, bb,
                     ga, gbt, (float*)d_out, B);
}

// Round 2
// 274.456 us; speedup vs baseline: 1.0200x; 1.0200x over previous
//
#include <hip/hip_runtime.h>
#include <hip/hip_bf16.h>
#include <float.h>

#define N_ORB 1024
#define KSEL 32
#define LEAK 0.01f
#define LOG2E 1.4426950408889634f

typedef float f32x2 __attribute__((ext_vector_type(2)));
// NOTE: never write (f32x2)(a, b) — in C++ that's a comma-expr cast that
// SPLATS b. Use f32x2{a, b}.

__device__ __forceinline__ float leaky(float x) { return x >= 0.0f ? x : LEAK * x; }

// ---- DPP helpers ----
template <int CTRL, int RM>
__device__ __forceinline__ int dpp0_i(int v) {  // masked-off rows contribute 0
  return __builtin_amdgcn_update_dpp(0, v, CTRL, RM, 0xF, true);
}
template <int CTRL>
__device__ __forceinline__ float dpp_zero(float v) {
  return __int_as_float(
      __builtin_amdgcn_update_dpp(0, __float_as_int(v), CTRL, 0xF, 0xF, true));
}
__device__ __forceinline__ float rdlane(float v, int l) {
  return __int_as_float(__builtin_amdgcn_readlane(__float_as_int(v), l));
}

// full 64-lane float sum, uniform result
__device__ __forceinline__ float wave_sum64_dpp(float v) {
  v += dpp_zero<0x111>(v);
  v += dpp_zero<0x112>(v);
  v += dpp_zero<0x114>(v);
  v += dpp_zero<0x118>(v);
  v += dpp_zero<0x142>(v);
  v += dpp_zero<0x143>(v);
  return rdlane(v, 63);
}
// full 64-lane int sum, uniform result
__device__ __forceinline__ int wave_isum64(int v) {
  v += dpp0_i<0x111, 0xF>(v);
  v += dpp0_i<0x112, 0xF>(v);
  v += dpp0_i<0x114, 0xF>(v);
  v += dpp0_i<0x118, 0xF>(v);
  v += dpp0_i<0x142, 0xF>(v);
  v += dpp0_i<0x143, 0xF>(v);
  return __builtin_amdgcn_readlane(v, 63);
}
// 64-lane inclusive prefix sum (int), per-lane result
__device__ __forceinline__ int wave_iscan64(int v) {
  v += dpp0_i<0x111, 0xF>(v);
  v += dpp0_i<0x112, 0xF>(v);
  v += dpp0_i<0x114, 0xF>(v);
  v += dpp0_i<0x118, 0xF>(v);
  v += dpp0_i<0x142, 0xA>(v);
  v += dpp0_i<0x143, 0xC>(v);
  return v;
}

// Successive-softmax chain for TWO rows packed in f32x2 (.x=row0,.y=row1),
// multiplicative form (w tracks exp(s)). Element j of a row = lane*16 + j.
// om clamp folds to the VOP3 clamp modifier; equivalent to ref's 1e-20 floor
// at fp32 (khot deltas <= 1e-20, far below any top-32 boundary).
// unroll 2: with the 128-VGPR budget (waves_per_eu pinned to the grid limit)
// the scheduler can overlap iteration t's kh updates with iteration t+1's
// tree+DPP reduce instead of stalling on the serial reduce every iteration.
__device__ void run_chain2(f32x2 w[16], f32x2 kh[16]) {
#pragma unroll
  for (int i = 0; i < 16; ++i) kh[i] = f32x2{0.0f, 0.0f};
  const f32x2 onev = f32x2{1.0f, 1.0f};
  const f32x2 zerov = f32x2{0.0f, 0.0f};
#pragma unroll 2
  for (int it = 0; it < KSEL; ++it) {
    f32x2 t0 = w[0] + w[1], t1 = w[2] + w[3], t2 = w[4] + w[5], t3 = w[6] + w[7];
    f32x2 t4 = w[8] + w[9], t5 = w[10] + w[11], t6 = w[12] + w[13], t7 = w[14] + w[15];
    t0 += t1; t2 += t3; t4 += t5; t6 += t7;
    t0 += t2; t4 += t6;
    t0 += t4;
    float Z0 = wave_sum64_dpp(t0.x);  // independent of Z1 -> interleaved issue
    float Z1 = wave_sum64_dpp(t0.y);
    Z0 = fmaxf(Z0, 1e-30f);
    Z1 = fmaxf(Z1, 1e-30f);
    float r0 = __builtin_amdgcn_rcpf(Z0);
    float r1 = __builtin_amdgcn_rcpf(Z1);
    float rZ0 = __builtin_fmaf(__builtin_fmaf(-Z0, r0, 1.0f), r0, r0);
    float rZ1 = __builtin_fmaf(__builtin_fmaf(-Z1, r1, 1.0f), r1, r1);
    const f32x2 rZ = f32x2{rZ0, rZ1};
#pragma unroll
    for (int i = 0; i < 16; ++i) {
      kh[i] = __builtin_elementwise_fma(w[i], rZ, kh[i]);
      f32x2 om = __builtin_elementwise_fma(-w[i], rZ, onev);
      om = __builtin_elementwise_min(__builtin_elementwise_max(om, zerov), onev);
      w[i] = w[i] * om;
    }
  }
}

// Tie path for one row (cold). jax stable tie semantics: all >T, then ==T
// in ascending global index ((lane<<4)|slot).
__device__ unsigned tie_mask16(const f32x2 kh[16], bool comp_y, unsigned T,
                               int lane) {
  unsigned gt = 0, eq = 0;
#pragma unroll
  for (int i = 0; i < 16; ++i) {
    const unsigned u = __float_as_uint(comp_y ? kh[i].y : kh[i].x);
    gt |= (u > T ? 1u : 0u) << i;
    eq |= (u == T ? 1u : 0u) << i;
  }
  const int n_gt = wave_isum64(__popc(gt));
  const int m = 32 - n_gt;  // uniform, >= 1 by search invariant
  const int pe = __popc(eq);
  const int be = wave_iscan64(pe) - pe;
  int need = m - be;
  need = need < 0 ? 0 : (need > pe ? pe : need);
  unsigned tk = 0;
  unsigned em = eq;
  for (int guard = 0; guard < 16; ++guard) {
    if (!__any(need > 0)) break;
    if (need > 0) {
      const int bpos = __ffs(em) - 1;
      tk |= 1u << bpos;
      em &= em - 1;
      --need;
    }
  }
  return gt | tk;
}

// Top-32 for both packed rows: joint binary search on the uint views
// (khot >= 0 -> order-isomorphic), ballot+popcll counting, early exit when
// both rows exact. Invariant (r6/r7, field-validated): tie path always
// completes exactly 32.
__device__ void top32_mask2(const f32x2 kh[16], int lane, unsigned& m0,
                            unsigned& m1) {
  unsigned lo0 = 0, lo1 = 0;
  bool ex0 = false, ex1 = false;
  for (int b = 30; b >= 0; --b) {
    const unsigned c0v = lo0 | (1u << b);
    const unsigned c1v = lo1 | (1u << b);
    int c0 = 0, c1 = 0;
#pragma unroll
    for (int i = 0; i < 16; ++i) {
      c0 += __popcll(__ballot(__float_as_uint(kh[i].x) >= c0v));
      c1 += __popcll(__ballot(__float_as_uint(kh[i].y) >= c1v));
    }
    if (!ex0 && c0 >= 32) { lo0 = c0v; ex0 = (c0 == 32); }
    if (!ex1 && c1 >= 32) { lo1 = c1v; ex1 = (c1 == 32); }
    if (ex0 && ex1) break;
  }

  if (ex0) {
    unsigned mk = 0;
#pragma unroll
    for (int i = 0; i < 16; ++i)
      mk |= (__float_as_uint(kh[i].x) >= lo0 ? 1u : 0u) << i;
    m0 = mk;
  } else {
    m0 = tie_mask16(kh, false, lo0, lane);
  }
  if (ex1) {
    unsigned mk = 0;
#pragma unroll
    for (int i = 0; i < 16; ++i)
      mk |= (__float_as_uint(kh[i].y) >= lo1 ? 1u : 0u) << i;
    m1 = mk;
  } else {
    m1 = tie_mask16(kh, true, lo1, lane);
  }
}

// Compact the 32 selected global indices into dst[0..31], ascending order.
__device__ __forceinline__ void compact_idx(unsigned mask, int lane,
                                            int* __restrict__ dst) {
  const int pe = __popc(mask);
  int base = wave_iscan64(pe) - pe;
  unsigned m = mask;
  while (m) {
    const int s = __ffs(m) - 1;
    m &= m - 1;
    dst[base++] = (lane << 4) | s;
  }
}

__device__ __forceinline__ void write_half(float* __restrict__ dst,
                                           unsigned mask, int lane) {
  float4* o4 = (float4*)dst;
#pragma unroll
  for (int q = 0; q < 4; ++q) {
    float4 o;
    o.x = ((mask >> (4 * q + 0)) & 1) ? 1.0f : 0.0f;
    o.y = ((mask >> (4 * q + 1)) & 1) ? 1.0f : 0.0f;
    o.z = ((mask >> (4 * q + 2)) & 1) ? 1.0f : 0.0f;
    o.w = ((mask >> (4 * q + 3)) & 1) ? 1.0f : 0.0f;
    o4[lane * 4 + q] = o;
  }
}

// ---- precompute, stage 1 (grid 256): the two length-1024 dot layers ----
extern "C" __global__ void pcfs_pre1(const float* __restrict__ ba,
                                     const float* __restrict__ W1a,
                                     const float* __restrict__ b1a,
                                     const float* __restrict__ bb,
                                     const float* __restrict__ W1b,
                                     float* __restrict__ ws) {
  const int b = blockIdx.x;
  const int t = threadIdx.x;
  float acc = 0.0f;
  if (b < 128) {
#pragma unroll
    for (int j = t; j < N_ORB; j += 256) acc += ba[j] * W1a[j * 128 + b];
  } else {
    const int n = b - 128;
#pragma unroll
    for (int j = t; j < N_ORB; j += 256) acc += bb[j] * W1b[j * 128 + n];
  }
  __shared__ float red[4];
  float wsum = wave_sum64_dpp(acc);
  if ((t & 63) == 0) red[t >> 6] = wsum;
  __syncthreads();
  if (t == 0) {
    float tot = red[0] + red[1] + red[2] + red[3];
    if (b < 128)
      ws[1152 + b] = leaky(tot + b1a[b]);
    else
      ws[N_ORB + (b - 128)] = tot;
  }
}

// ---- precompute, stage 2 (1 block x 1024): h2 + alpha const logits ----
extern "C" __global__ void pcfs_pre2(const float* __restrict__ ba,
                                     const float* __restrict__ W2a,
                                     const float* __restrict__ b2a,
                                     const float* __restrict__ W3a,
                                     const float* __restrict__ b3a,
                                     float* __restrict__ ws) {
  __shared__ float h1[128];
  __shared__ float h2[64];
  const int t = threadIdx.x;
  if (t < 128) h1[t] = ws[1152 + t];
  __syncthreads();
  if (t < 64) {
    float acc = b2a[t];
#pragma unroll 8
    for (int n = 0; n < 128; ++n) acc += h1[n] * W2a[n * 64 + t];
    h2[t] = leaky(acc);
  }
  __syncthreads();
  float acc = b3a[t];
#pragma unroll 8
  for (int m = 0; m < 64; ++m) acc += h2[m] * W3a[m * N_ORB + t];
  ws[t] = acc + ba[t];  // + base_a
}

// One wave per PAIR of batch rows (.x=row0, .y=row1 in every f32x2).
// waves_per_eu(4,4): the grid (4 blocks/CU) caps occupancy at 4 waves/EU;
// pinning the target stops the backend from squeezing regalloc to 64 VGPRs
// (8-wave tier the grid can never reach) and spilling chain state to scratch.
extern "C" __global__ void __launch_bounds__(256)
    __attribute__((amdgpu_waves_per_eu(4, 4))) pcfs_sampler(
    const float* __restrict__ ws, const float* __restrict__ Wc,
    const float* __restrict__ bc, const float* __restrict__ W1b,
    const float* __restrict__ b1b, const float* __restrict__ W2b,
    const float* __restrict__ b2b, const float* __restrict__ W3b,
    const float* __restrict__ b3b, const float* __restrict__ bb,
    const float* __restrict__ g_alpha, const float* __restrict__ g_beta,
    float* __restrict__ out, int B) {
  __shared__ int sidx[4][64];  // per-wave: [0..31]=row0 idxs, [32..63]=row1
  const int wave = threadIdx.x >> 6;
  const int lane = threadIdx.x & 63;
  const int pair = blockIdx.x * 4 + wave;
  const int row0 = pair * 2;
  if (row0 >= B) return;
  const bool have1 = (row0 + 1 < B);
  const int row1 = have1 ? row0 + 1 : row0;

  f32x2 w[16], kh[16];

  // ---- alpha chains: w = exp2((const_logits + gumbel) * log2e), 2 rows ----
  {
    const float4* c4 = (const float4*)ws;
    const float4* g40 = (const float4*)(g_alpha + (size_t)row0 * N_ORB);
    const float4* g41 = (const float4*)(g_alpha + (size_t)row1 * N_ORB);
#pragma unroll
    for (int q = 0; q < 4; ++q) {
      float4 c = c4[lane * 4 + q];
      float4 g0 = g40[lane * 4 + q];
      float4 g1 = g41[lane * 4 + q];
      w[4 * q + 0] = f32x2{__builtin_amdgcn_exp2f((c.x + g0.x) * LOG2E),
                           __builtin_amdgcn_exp2f((c.x + g1.x) * LOG2E)};
      w[4 * q + 1] = f32x2{__builtin_amdgcn_exp2f((c.y + g0.y) * LOG2E),
                           __builtin_amdgcn_exp2f((c.y + g1.y) * LOG2E)};
      w[4 * q + 2] = f32x2{__builtin_amdgcn_exp2f((c.z + g0.z) * LOG2E),
                           __builtin_amdgcn_exp2f((c.z + g1.z) * LOG2E)};
      w[4 * q + 3] = f32x2{__builtin_amdgcn_exp2f((c.w + g0.w) * LOG2E),
                           __builtin_amdgcn_exp2f((c.w + g1.w) * LOG2E)};
    }
  }
  run_chain2(w, kh);
  unsigned am0, am1;
  top32_mask2(kh, lane, am0, am1);

  // write alpha halves (hard config: exact 0/1)
  write_half(out + (size_t)row0 * (2 * N_ORB), am0, lane);
  if (have1) write_half(out + (size_t)row1 * (2 * N_ORB), am1, lane);

  // ---- ctx = alpha_config @ Wc + bc, per row (LDS compact + fixed trip) ----
  compact_idx(am0, lane, &sidx[wave][0]);
  compact_idx(am1, lane, &sidx[wave][32]);
  const int vi0 = sidx[wave][lane & 31];
  const int vi1 = sidx[wave][32 + (lane & 31)];
  const float bcv = bc[lane & 31];
  float ctx0 = bcv, ctx1 = bcv;
#pragma unroll
  for (int r = 0; r < 32; ++r) {
    const int i0 = __builtin_amdgcn_readlane(vi0, r);  // uniform
    const int i1 = __builtin_amdgcn_readlane(vi1, r);
    ctx0 += Wc[i0 * 32 + (lane & 31)];
    ctx1 += Wc[i1 * 32 + (lane & 31)];
  }

  // ---- h1 = leaky(base_b@W1b[0:1024] + ctx@W1b[1024:1056] + b1b) ----
  f32x2 h1a, h1b_;
  {
    const float ia = b1b[lane] + ws[N_ORB + lane];
    const float ib = b1b[lane + 64] + ws[N_ORB + lane + 64];
    h1a = f32x2{ia, ia};
    h1b_ = f32x2{ib, ib};
  }
#pragma unroll 4
  for (int c = 0; c < 32; ++c) {
    const f32x2 cv = f32x2{rdlane(ctx0, c), rdlane(ctx1, c)};
    const float* wr = W1b + (size_t)(N_ORB + c) * 128;
    const float wa = wr[lane], wb = wr[lane + 64];
    h1a = __builtin_elementwise_fma(f32x2{wa, wa}, cv, h1a);
    h1b_ = __builtin_elementwise_fma(f32x2{wb, wb}, cv, h1b_);
  }
  h1a = f32x2{leaky(h1a.x), leaky(h1a.y)};
  h1b_ = f32x2{leaky(h1b_.x), leaky(h1b_.y)};

  // ---- h2 = leaky(h1 @ W2b + b2b): 4 partial accumulators (32-deep
  // chains instead of 128-deep) ----
  f32x2 h2p0, h2p1, h2p2, h2p3;
  {
    const float i2 = b2b[lane];
    h2p0 = f32x2{i2, i2};
    h2p1 = f32x2{0.0f, 0.0f};
    h2p2 = f32x2{0.0f, 0.0f};
    h2p3 = f32x2{0.0f, 0.0f};
  }
#pragma unroll 4
  for (int n = 0; n < 64; n += 4) {
    const f32x2 v0 = f32x2{rdlane(h1a.x, n + 0), rdlane(h1a.y, n + 0)};
    const f32x2 v1 = f32x2{rdlane(h1a.x, n + 1), rdlane(h1a.y, n + 1)};
    const f32x2 v2 = f32x2{rdlane(h1a.x, n + 2), rdlane(h1a.y, n + 2)};
    const f32x2 v3 = f32x2{rdlane(h1a.x, n + 3), rdlane(h1a.y, n + 3)};
    const float w0 = W2b[(n + 0) * 64 + lane];
    const float w1 = W2b[(n + 1) * 64 + lane];
    const float w2 = W2b[(n + 2) * 64 + lane];
    const float w3 = W2b[(n + 3) * 64 + lane];
    h2p0 = __builtin_elementwise_fma(f32x2{w0, w0}, v0, h2p0);
    h2p1 = __builtin_elementwise_fma(f32x2{w1, w1}, v1, h2p1);
    h2p2 = __builtin_elementwise_fma(f32x2{w2, w2}, v2, h2p2);
    h2p3 = __builtin_elementwise_fma(f32x2{w3, w3}, v3, h2p3);
  }
#pragma unroll 4
  for (int n = 0; n < 64; n += 4) {
    const f32x2 v0 = f32x2{rdlane(h1b_.x, n + 0), rdlane(h1b_.y, n + 0)};
    const f32x2 v1 = f32x2{rdlane(h1b_.x, n + 1), rdlane(h1b_.y, n + 1)};
    const f32x2 v2 = f32x2{rdlane(h1b_.x, n + 2), rdlane(h1b_.y, n + 2)};
    const f32x2 v3 = f32x2{rdlane(h1b_.x, n + 3), rdlane(h1b_.y, n + 3)};
    const float w0 = W2b[(n + 64 + 0) * 64 + lane];
    const float w1 = W2b[(n + 64 + 1) * 64 + lane];
    const float w2 = W2b[(n + 64 + 2) * 64 + lane];
    const float w3 = W2b[(n + 64 + 3) * 64 + lane];
    h2p0 = __builtin_elementwise_fma(f32x2{w0, w0}, v0, h2p0);
    h2p1 = __builtin_elementwise_fma(f32x2{w1, w1}, v1, h2p1);
    h2p2 = __builtin_elementwise_fma(f32x2{w2, w2}, v2, h2p2);
    h2p3 = __builtin_elementwise_fma(f32x2{w3, w3}, v3, h2p3);
  }
  f32x2 h2v = (h2p0 + h2p1) + (h2p2 + h2p3);
  h2v = f32x2{leaky(h2v.x), leaky(h2v.y)};

  // ---- beta logits: acc (in w[]) = h2 @ W3b + b3b; shared W3b loads,
  // unrolled x4 so 16 float4 loads pipeline per group ----
  {
    const float4* b4 = (const float4*)b3b;
#pragma unroll
    for (int q = 0; q < 4; ++q) {
      float4 b = b4[lane * 4 + q];
      w[4 * q + 0] = f32x2{b.x, b.x};
      w[4 * q + 1] = f32x2{b.y, b.y};
      w[4 * q + 2] = f32x2{b.z, b.z};
      w[4 * q + 3] = f32x2{b.w, b.w};
    }
  }
#pragma unroll 4
  for (int m = 0; m < 64; ++m) {
    const f32x2 hm = f32x2{rdlane(h2v.x, m), rdlane(h2v.y, m)};
    const float4* w4 = (const float4*)(W3b + m * N_ORB);
#pragma unroll
    for (int q = 0; q < 4; ++q) {
      float4 wv = w4[lane * 4 + q];
      w[4 * q + 0] = __builtin_elementwise_fma(f32x2{wv.x, wv.x}, hm, w[4 * q + 0]);
      w[4 * q + 1] = __builtin_elementwise_fma(f32x2{wv.y, wv.y}, hm, w[4 * q + 1]);
      w[4 * q + 2] = __builtin_elementwise_fma(f32x2{wv.z, wv.z}, hm, w[4 * q + 2]);
      w[4 * q + 3] = __builtin_elementwise_fma(f32x2{wv.w, wv.w}, hm, w[4 * q + 3]);
    }
  }
  // + base_b + gumbel (loaded here inline: one L2/L3 round-trip per wave is
  // ~600 cy of a ~365k-cy wave lifetime; holding 32 VGPRs of prefetch across
  // the whole alpha phase was what blew the register budget) ----
  {
    const float4* bb4 = (const float4*)bb;
    const float4* g40 = (const float4*)(g_beta + (size_t)row0 * N_ORB);
    const float4* g41 = (const float4*)(g_beta + (size_t)row1 * N_ORB);
#pragma unroll
    for (int q = 0; q < 4; ++q) {
      float4 b = bb4[lane * 4 + q];
      const float4 g0 = g40[lane * 4 + q];
      const float4 g1 = g41[lane * 4 + q];
      w[4 * q + 0] = f32x2{
          __builtin_amdgcn_exp2f((w[4 * q + 0].x + b.x + g0.x) * LOG2E),
          __builtin_amdgcn_exp2f((w[4 * q + 0].y + b.x + g1.x) * LOG2E)};
      w[4 * q + 1] = f32x2{
          __builtin_amdgcn_exp2f((w[4 * q + 1].x + b.y + g0.y) * LOG2E),
          __builtin_amdgcn_exp2f((w[4 * q + 1].y + b.y + g1.y) * LOG2E)};
      w[4 * q + 2] = f32x2{
          __builtin_amdgcn_exp2f((w[4 * q + 2].x + b.z + g0.z) * LOG2E),
          __builtin_amdgcn_exp2f((w[4 * q + 2].y + b.z + g1.z) * LOG2E)};
      w[4 * q + 3] = f32x2{
          __builtin_amdgcn_exp2f((w[4 * q + 3].x + b.w + g0.w) * LOG2E),
          __builtin_amdgcn_exp2f((w[4 * q + 3].y + b.w + g1.w) * LOG2E)};
    }
  }
  run_chain2(w, kh);
  unsigned bm0, bm1;
  top32_mask2(kh, lane, bm0, bm1);

  write_half(out + (size_t)row0 * (2 * N_ORB) + N_ORB, bm0, lane);
  if (have1) write_half(out + (size_t)row1 * (2 * N_ORB) + N_ORB, bm1, lane);
}

extern "C" void kernel_launch(void* const* d_in, const int* in_sizes, int n_in,
                              void* d_out, int out_size, void* d_ws, size_t ws_size,
                              hipStream_t stream) {
  const float* ba  = (const float*)d_in[0];
  const float* W1a = (const float*)d_in[1];
  const float* b1a = (const float*)d_in[2];
  const float* W2a = (const float*)d_in[3];
  const float* b2a = (const float*)d_in[4];
  const float* W3a = (const float*)d_in[5];
  const float* b3a = (const float*)d_in[6];
  const float* bb  = (const float*)d_in[7];
  const float* Wc  = (const float*)d_in[8];
  const float* bc  = (const float*)d_in[9];
  const float* W1b = (const float*)d_in[10];
  const float* b1b = (const float*)d_in[11];
  const float* W2b = (const float*)d_in[12];
  const float* b2b = (const float*)d_in[13];
  const float* W3b = (const float*)d_in[14];
  const float* b3b = (const float*)d_in[15];
  const float* ga  = (const float*)d_in[16];
  const float* gbt = (const float*)d_in[17];
  const int B = in_sizes[16] / N_ORB;
  float* ws = (float*)d_ws;

  hipLaunchKernelGGL(pcfs_pre1, dim3(256), dim3(256), 0, stream,
                     ba, W1a, b1a, bb, W1b, ws);
  hipLaunchKernelGGL(pcfs_pre2, dim3(1), dim3(1024), 0, stream,
                     ba, W2a, b2a, W3a, b3a, ws);
  const int pairs = (B + 1) / 2;
  hipLaunchKernelGGL(pcfs_sampler, dim3((pairs + 3) / 4), dim3(256), 0, stream,
                     ws, Wc, bc, W1b, b1b, W2b, b2b, W3b, b3b, bb,
                     ga, gbt, (float*)d_out, B);
}